// Round 12
// baseline (583.564 us; speedup 1.0000x reference)
//
#include <hip/hip_runtime.h>
#include <cstdint>

#define K_IN   4096
#define N_OUT  4096
#define M_ROWS 16384
#define RANK   8
#define LSCALE 1.0f    // alpha/rank = 8/8
#define NT     64      // K_IN / 64  (BK=64 K-tiles)
#define ROWB   8192    // K_IN * 2 bytes per global row
#define AHALF  1048576 // 128 rows * ROWB

typedef __attribute__((ext_vector_type(8))) short  short8;
typedef __attribute__((ext_vector_type(4))) float  floatx4;

__device__ __forceinline__ unsigned short f2bf(float f) {
  uint32_t u = __float_as_uint(f);
  u += 0x7FFFu + ((u >> 16) & 1u);
  return (unsigned short)(u >> 16);
}

__global__ __launch_bounds__(256) void fold_w_kernel(
    const float* __restrict__ W, const float* __restrict__ lA,
    const float* __restrict__ lB, unsigned short* __restrict__ Weff) {
  int idx = blockIdx.x * 256 + threadIdx.x;
  int o = idx >> 10;
  int k = (idx & 1023) << 2;
  float4 w = *reinterpret_cast<const float4*>(W + (size_t)o * K_IN + k);
#pragma unroll
  for (int r = 0; r < RANK; ++r) {
    float s = LSCALE * lB[o * RANK + r];
    float4 a = *reinterpret_cast<const float4*>(lA + r * K_IN + k);
    w.x += s * a.x; w.y += s * a.y; w.z += s * a.z; w.w += s * a.w;
  }
  ushort4 p;
  p.x = f2bf(w.x); p.y = f2bf(w.y); p.z = f2bf(w.z); p.w = f2bf(w.w);
  *reinterpret_cast<ushort4*>(Weff + (size_t)o * K_IN + k) = p;
}

__global__ __launch_bounds__(256) void cvt_x_kernel(
    const float* __restrict__ x, unsigned short* __restrict__ xb) {
  size_t i = ((size_t)blockIdx.x * 256 + threadIdx.x) * 8;
  float4 a = *reinterpret_cast<const float4*>(x + i);
  float4 c = *reinterpret_cast<const float4*>(x + i + 4);
  uint4 v;
  v.x = (uint32_t)f2bf(a.x) | ((uint32_t)f2bf(a.y) << 16);
  v.y = (uint32_t)f2bf(a.z) | ((uint32_t)f2bf(a.w) << 16);
  v.z = (uint32_t)f2bf(c.x) | ((uint32_t)f2bf(c.y) << 16);
  v.w = (uint32_t)f2bf(c.z) | ((uint32_t)f2bf(c.w) << 16);
  *reinterpret_cast<uint4*>(xb + i) = v;
}

__device__ __forceinline__ void gload_lds16(const void* g, void* l) {
  __builtin_amdgcn_global_load_lds(
      (const __attribute__((address_space(1))) void*)g,
      (__attribute__((address_space(3))) void*)l, 16, 0, 0);
}

#define BAR() do { asm volatile("" ::: "memory");                         \
    __builtin_amdgcn_s_barrier();                                         \
    asm volatile("" ::: "memory"); } while (0)

// inline-asm LDS read: base VGPR + literal offset (R11-validated).
#define DSR(DST, ADDR, IMM)                                               \
  asm volatile("ds_read_b128 %0, %1 offset:%2"                            \
               : "=v"(DST) : "v"(ADDR), "i"(IMM))
// counted lgkm wait + sched_barrier (rule 18): DS returns are in-order per
// wave, so lgkmcnt(N) certifies all but the newest N ds_reads.
#define LGKM(N) do {                                                      \
    asm volatile("s_waitcnt lgkmcnt(" #N ")" ::: "memory");               \
    __builtin_amdgcn_sched_barrier(0); } while (0)

// ---------------------------------------------------------------------------
// 256x256 tile, BK=64, 512 threads (8 waves 2Mx4N). R12: PIPELINED READS.
// R11 measured wall 4734 cyc/K-tile/CU = MFMA 2483 + LDS 2300 ADDITIVE: the
// [reads|BAR|lgkm0|MFMA|BAR] skeleton leaves zero ds_reads in flight during
// every MFMA cluster. This round overlaps them with counted lgkmcnt waits.
// Quadrant order (0,0)->(0,1)->(1,0)->(1,1); fixed frag sets:
//   afA=A(mq0), afB=A(mq1), bfC=B(nq0), bfD=B(nq1)   (96 frag VGPRs)
// Per tile t (4 barriers, one per phase end):
//  P0: issue bfD(4)+afB(8); STAGE(t+1,h3); LGKM(12)[afA,bfC ready];
//      MFMA(0,0)[afA,bfC]; BAR
//  P1: LGKM(8)[bfD ready]; MFMA(0,1)[afA,bfD]; BAR          (afA dead)
//  P2: LGKM(0)[afB ready]; MFMA(1,0)[afB,bfC]; vmcnt(0) cert t+1; BAR
//      -> after this BAR, ALL waves' reads of buf t&1 are complete
//  P3: toggle parity; issue afA(8)+bfC(4) for t+1 [certified at P2];
//      STAGE(t+2, h0,h1,h2) [writes buf t&1 - race-FREE: all reads done
//      at P2 BAR, stricter than R8-R11's latency-window argument];
//      MFMA(1,1)[afB,bfD]; BAR
// Every MFMA cluster runs with ~12 reads/wave in flight -> LDS (2300/tile)
// hides under MFMA (2483/tile). Barriers halved 8->4.
// vmcnt ledger: stages/tile = {(t+1,h3) @P0} + {(t+2,h0..h2) @P3}; at P2(t)
// in-flight = (t+1,h0..h3) issued >=2 phases prior -> vmcnt(0) nearly free,
// and tile t+1 is certified before its first reads at P3(t).
// Guards: P0 stage t<=NT-2; P3 stages t<=NT-3; P3 reads t<=NT-2;
// P2 cert t<=NT-2. Prologue: stage (0,h0..h3),(1,h0..h2)=7; vmcnt(6)
// retires tile 0; BAR; preload afA,bfC of tile 0.
// Swizzle LDSWZ2 (R9: conflicts=0.0) via 4 base regs (R11: carry-free imms).
// ---------------------------------------------------------------------------
__global__ __launch_bounds__(512, 2) void gemm256_kernel(
    const unsigned short* __restrict__ Xb, const unsigned short* __restrict__ Wb,
    const float* __restrict__ bias, float* __restrict__ out) {
  __shared__ alignas(16) char lds[2 * 65536];   // 128 KiB

  const int tid  = threadIdx.x;
  const int wave = tid >> 6, lane = tid & 63;
  const int wr = wave >> 2, wc = wave & 3;      // 2 (M) x 4 (N) wave grid
  const int l15 = lane & 15, sq = lane >> 4;

  // XCD swizzle: 1024 blocks (%8==0), contiguous 128-tile chunk per XCD
  int bx  = blockIdx.x;
  int sbx = (bx & 7) * 128 + (bx >> 3);
  const int mt = sbx >> 4;   // 0..63
  const int nt = sbx & 15;   // 0..15

  // staging source pre-swizzle (proven R9/R11)
  const int rstg = tid >> 3;
  const int cbst = (((tid & 7) ^ ((tid >> 3) & 7)) << 4);
  const char* aBase = (const char*)Xb + (size_t)(mt * 256 + rstg) * ROWB + cbst;
  const char* bBase = (const char*)Wb + (size_t)(nt * 256 + rstg) * ROWB + cbst;

  // STAGE with literal half index HH (0,1 = A halves; 2,3 = B halves)
#define STAGE_TH(TH, HH) do {                                             \
    const char* src_ = ((HH) < 2 ? aBase + (size_t)(HH) * AHALF           \
                                 : bBase + (size_t)((HH) - 2) * AHALF)    \
                       + (TH) * 128;                                      \
    char* dst_ = lds + ((TH) & 1) * 65536 + (HH) * 16384 + tid * 16;      \
    gload_lds16(src_, dst_);                                              \
    gload_lds16(src_ + (size_t)64 * ROWB, dst_ + 8192);                   \
  } while (0)

  // LDS read bases (R11 fix: ks folded inside XOR; imms are pure row terms)
  const unsigned ldsb = (unsigned)(unsigned long long)
      (__attribute__((address_space(3))) char*)lds;
  const unsigned X = (unsigned)((l15 & 7) << 4);
  const unsigned aRow = ldsb + wr * 16384 + l15 * 128;
  const unsigned bRow = ldsb + (2 + (wc >> 1)) * 16384 + (wc & 1) * 8192
                        + l15 * 128;
  unsigned aCur0 = aRow + ((0u  + sq * 16) ^ X);
  unsigned aCur1 = aRow + ((64u + sq * 16) ^ X);
  unsigned bCur0 = bRow + ((0u  + sq * 16) ^ X);
  unsigned bCur1 = bRow + ((64u + sq * 16) ^ X);

#define LOAD_A(DST, MQ) do {                                              \
    _Pragma("unroll")                                                     \
    for (int fi = 0; fi < 4; ++fi)                                        \
      DSR(DST[fi],     aCur0, (MQ) * 8192 + fi * 2048);                   \
    _Pragma("unroll")                                                     \
    for (int fi = 0; fi < 4; ++fi)                                        \
      DSR(DST[4 + fi], aCur1, (MQ) * 8192 + fi * 2048);                   \
  } while (0)
#define LOAD_B(DST, NQ) do {                                              \
    _Pragma("unroll")                                                     \
    for (int fj = 0; fj < 2; ++fj)                                        \
      DSR(DST[fj],     bCur0, (NQ) * 4096 + fj * 2048);                   \
    _Pragma("unroll")                                                     \
    for (int fj = 0; fj < 2; ++fj)                                        \
      DSR(DST[2 + fj], bCur1, (NQ) * 4096 + fj * 2048);                   \
  } while (0)
#define MFMA_Q(MQ, NQ, AF, BF) do {                                       \
    __builtin_amdgcn_s_setprio(1);                                        \
    _Pragma("unroll")                                                     \
    for (int ks = 0; ks < 2; ++ks)                                        \
      _Pragma("unroll")                                                   \
      for (int fi = 0; fi < 4; ++fi)                                      \
        _Pragma("unroll")                                                 \
        for (int fj = 0; fj < 2; ++fj)                                    \
          acc[(MQ) * 4 + fi][(NQ) * 2 + fj] =                             \
              __builtin_amdgcn_mfma_f32_16x16x32_bf16(                    \
                  AF[ks * 4 + fi], BF[ks * 2 + fj],                       \
                  acc[(MQ) * 4 + fi][(NQ) * 2 + fj], 0, 0, 0);            \
    __builtin_amdgcn_s_setprio(0); } while (0)

  floatx4 acc[8][4];
#pragma unroll
  for (int i = 0; i < 8; ++i)
#pragma unroll
    for (int j = 0; j < 4; ++j)
      acc[i][j] = (floatx4){0.f, 0.f, 0.f, 0.f};

  // prologue: 7 half-tiles; vmcnt(6) retires tile 0; preload afA,bfC(tile 0)
  STAGE_TH(0, 0); STAGE_TH(0, 1); STAGE_TH(0, 2); STAGE_TH(0, 3);
  STAGE_TH(1, 0); STAGE_TH(1, 1); STAGE_TH(1, 2);
  asm volatile("s_waitcnt vmcnt(6)" ::: "memory");
  BAR();

  short8 afA[8], afB[8], bfC[4], bfD[4];
  LOAD_A(afA, 0);
  LOAD_B(bfC, 0);

  for (int t = 0; t < NT; ++t) {
    // ---- P0: issue current-tile bfD,afB; MFMA(0,0)
    LOAD_B(bfD, 1);
    LOAD_A(afB, 1);
    if (t <= NT - 2) STAGE_TH(t + 1, 3);
    LGKM(12);                       // afA,bfC landed (12 newer outstanding)
    MFMA_Q(0, 0, afA, bfC);
    BAR();

    // ---- P1: MFMA(0,1); afA dies
    LGKM(8);                        // bfD landed
    MFMA_Q(0, 1, afA, bfD);
    BAR();

    // ---- P2: MFMA(1,0); bfC dies; cert tile t+1
    LGKM(0);                        // afB landed
    MFMA_Q(1, 0, afB, bfC);
    if (t <= NT - 2) asm volatile("s_waitcnt vmcnt(0)" ::: "memory");
    BAR();                          // all waves done reading buf t&1

    // ---- P3: issue next-tile afA,bfC; stage into buf t&1 (race-free);
    //          MFMA(1,1)
    if (t <= NT - 2) {
      aCur0 ^= 65536u; aCur1 ^= 65536u; bCur0 ^= 65536u; bCur1 ^= 65536u;
      LOAD_A(afA, 0);
      LOAD_B(bfC, 0);
    }
    if (t <= NT - 3) {
      STAGE_TH(t + 2, 0); STAGE_TH(t + 2, 1); STAGE_TH(t + 2, 2);
    }
    __builtin_amdgcn_sched_barrier(0);
    MFMA_Q(1, 1, afB, bfD);
    BAR();
  }
#undef STAGE_TH
#undef LOAD_A
#undef LOAD_B
#undef MFMA_Q

  // epilogue: C/D layout col=lane&15, row=(lane>>4)*4+reg (m89/m91 verified)
  const int row0 = mt * 256 + wr * 128 + sq * 4;
  const int col0 = nt * 256 + wc * 64 + l15;
#pragma unroll
  for (int j = 0; j < 4; ++j) {
    int col = col0 + j * 16;
    float bv = bias[col];
#pragma unroll
    for (int i = 0; i < 8; ++i) {
      int rowb = row0 + i * 16;
#pragma unroll
      for (int rr = 0; rr < 4; ++rr)
        out[(size_t)(rowb + rr) * N_OUT + col] = acc[i][j][rr] + bv;
    }
  }
}

// self-contained correct fallback (only if ws too small): tiled fp32
__global__ __launch_bounds__(256) void fallback_kernel(
    const float* __restrict__ x, const float* __restrict__ W,
    const float* __restrict__ bias, const float* __restrict__ lA,
    const float* __restrict__ lB, float* __restrict__ out) {
  __shared__ float Xs[64][17];
  __shared__ float Ws[64][17];
  int tid = threadIdx.x;
  int tx = tid & 15, ty = tid >> 4;
  int bm = blockIdx.y * 64, bn = blockIdx.x * 64;
  float acc[4][4] = {};
  for (int k0 = 0; k0 < K_IN; k0 += 16) {
#pragma unroll
    for (int q = 0; q < 4; ++q) {
      int flat = q * 256 + tid;
      int r = flat >> 4, c = flat & 15;
      Xs[r][c] = x[(size_t)(bm + r) * K_IN + k0 + c];
      float w = W[(size_t)(bn + r) * K_IN + k0 + c];
#pragma unroll
      for (int rr = 0; rr < RANK; ++rr)
        w += LSCALE * lB[(bn + r) * RANK + rr] * lA[rr * K_IN + k0 + c];
      Ws[r][c] = w;
    }
    __syncthreads();
#pragma unroll
    for (int kk = 0; kk < 16; ++kk) {
      float av[4], bv[4];
#pragma unroll
      for (int i = 0; i < 4; ++i) av[i] = Xs[ty * 4 + i][kk];
#pragma unroll
      for (int j = 0; j < 4; ++j) bv[j] = Ws[tx * 4 + j][kk];
#pragma unroll
      for (int i = 0; i < 4; ++i)
#pragma unroll
        for (int j = 0; j < 4; ++j) acc[i][j] += av[i] * bv[j];
    }
    __syncthreads();
  }
#pragma unroll
  for (int i = 0; i < 4; ++i)
#pragma unroll
    for (int j = 0; j < 4; ++j)
      out[(size_t)(bm + ty * 4 + i) * N_OUT + bn + tx * 4 + j] =
          acc[i][j] + bias[bn + tx * 4 + j];
}

extern "C" void kernel_launch(void* const* d_in, const int* in_sizes, int n_in,
                              void* d_out, int out_size, void* d_ws, size_t ws_size,
                              hipStream_t stream) {
  const float* x  = (const float*)d_in[0];
  const float* W  = (const float*)d_in[1];
  const float* b  = (const float*)d_in[2];
  const float* lA = (const float*)d_in[3];
  const float* lB = (const float*)d_in[4];
  float* out = (float*)d_out;

  const size_t weff_bytes = (size_t)N_OUT * K_IN * 2;    // 32 MB
  const size_t xb_bytes   = (size_t)M_ROWS * K_IN * 2;   // 128 MB

  if (ws_size >= weff_bytes + xb_bytes) {
    unsigned short* Weff = (unsigned short*)d_ws;
    unsigned short* Xb   = (unsigned short*)((char*)d_ws + weff_bytes);
    fold_w_kernel<<<(int)(((size_t)N_OUT * K_IN / 4) / 256), 256, 0, stream>>>(W, lA, lB, Weff);
    cvt_x_kernel<<<(int)(((size_t)M_ROWS * K_IN / 8) / 256), 256, 0, stream>>>(x, Xb);
    gemm256_kernel<<<(M_ROWS / 256) * (N_OUT / 256), 512, 0, stream>>>(Xb, Weff, b, out);
  } else {
    dim3 grid(N_OUT / 64, M_ROWS / 64);
    fallback_kernel<<<grid, 256, 0, stream>>>(x, W, b, lA, lB, out);
  }
}